// Round 18
// baseline (121.826 us; speedup 1.0000x reference)
//
#include <hip/hip_runtime.h>

// BasicBlock: y = relu(bn2(conv2(relu(bn1(conv1(x, we1))), we2)) + x)
// we{1,2} = sum_e alpha[e]*w{1,2}[e].
//
// bf16 implicit-GEMM conv, mfma_f32_16x16x32_bf16, staged from padded,
// chunk-swizzled NHWC bf16 images (slot = c8 ^ ((2h+w)&7) within 128B px).
//
// R18 = R17 (persistent conv blocks, 119.3us) + three mechanical fixes:
//  (1) P0 grid 632 (8x79): LDS 46KB -> 3 blocks/CU resident (vs 2), 1.5x
//      stage bytes in flight; ~5 tiles/block, 608x5+24x4 near-balanced.
//  (2) transform grid 1792, 2 rows/block: all-resident (was 3584 blocks vs
//      ~2048 capacity = 1.75 scheduling rounds -> 43%-idle tail round).
//  (3) border_zero + prep merged into one setup kernel (5 -> 4 launches).
// P1 unchanged from R17 (78.8KB LDS caps 2/CU; residual single-buffer races).
// Counted gates (loads-only sound): P0 vmcnt(6|5), P1 vmcnt(10|9).

typedef __bf16 bf16x8 __attribute__((ext_vector_type(8)));
typedef float f32x4 __attribute__((ext_vector_type(4)));
typedef unsigned short u16;
typedef u16 u16x8 __attribute__((ext_vector_type(8)));

#define NH 112
#define NW 112
#define PH 114
#define PW 114
#define PROWB (PW * 128)  // 14592 bytes per padded NHWC row
#define BUFB 23040        // y1/x window buffer: 10 rows * 18 px * 128 B
#define NTILES 3136       // 32 images * 98 tiles

#define WAITVM(n) asm volatile("s_waitcnt vmcnt(" #n ")" ::: "memory")
#define SCHEDB __builtin_amdgcn_sched_barrier(0)

__device__ __forceinline__ u16 f2b(float f) {
  unsigned u = __builtin_bit_cast(unsigned, f);
  u += 0x7FFFu + ((u >> 16) & 1u);
  return (u16)(u >> 16);
}
__device__ __forceinline__ float b2f(u16 b) {
  unsigned u = ((unsigned)b) << 16;
  return __builtin_bit_cast(float, u);
}

__device__ __forceinline__ void gl_lds16(const void* g, void* l) {
  __builtin_amdgcn_global_load_lds(
      (const __attribute__((address_space(1))) unsigned int*)g,
      (__attribute__((address_space(3))) unsigned int*)l, 16, 0, 0);
}

// ---------------------------------------------------------------------------
// setup: zero 1-px borders of xpad & y1pad (blocks 0..903) + fold experts /
// BN constants (blocks 904..1047). One launch instead of two.
__global__ void setup_kernel(
    u16* __restrict__ a, u16* __restrict__ bbuf,
    const float* __restrict__ w1, const float* __restrict__ w2,
    const float* __restrict__ alpha,
    const float* __restrict__ g1, const float* __restrict__ b1,
    const float* __restrict__ m1, const float* __restrict__ v1,
    const float* __restrict__ g2, const float* __restrict__ b2,
    const float* __restrict__ m2, const float* __restrict__ v2,
    u16* __restrict__ weff1, u16* __restrict__ weff2, float* __restrict__ bnc) {
  int bid = blockIdx.x, tid = threadIdx.x;
  if (bid < 904) {
    int idx = bid * 256 + tid;  // 2*32*452*8 = 231424 chunks
    if (idx >= 231424) return;
    int c8 = idx & 7;
    int t = idx >> 3;
    int buf = t >= 14464;
    t -= buf * 14464;
    int img = t / 452, e = t % 452;
    int h, w;
    if (e < 114) { h = 0; w = e; }
    else if (e < 228) { h = 113; w = e - 114; }
    else if (e < 340) { h = e - 227; w = 0; }
    else { h = e - 339; w = 113; }
    u16* base = buf ? bbuf : a;
    u16x8 z = {0, 0, 0, 0, 0, 0, 0, 0};
    *reinterpret_cast<u16x8*>(base + (((long)img * PH + h) * PW + w) * 64 + c8 * 8) = z;
    return;
  }
  int idx = (bid - 904) * 256 + tid;  // 36864 weights
  if (idx < 36864) {
    int i = idx & 63;
    int o = (idx >> 6) & 63;
    int kpos = idx >> 12;
    int base = (o * 64 + i) * 9 + kpos;  // src [E][O][I][3][3]
    float a1 = 0.f, a2 = 0.f;
#pragma unroll
    for (int e = 0; e < 10; ++e) {
      float al = alpha[e];
      a1 += al * w1[e * 36864 + base];
      a2 += al * w2[e * 36864 + base];
    }
    weff1[idx] = f2b(a1);
    weff2[idx] = f2b(a2);
  }
  if (bid == 904 && tid < 64) {
    int c = tid;
    float i1 = g1[c] * rsqrtf(v1[c] + 1e-5f);
    float i2 = g2[c] * rsqrtf(v2[c] + 1e-5f);
    bnc[c] = i1;
    bnc[64 + c] = b1[c] - m1[c] * i1;
    bnc[128 + c] = i2;
    bnc[192 + c] = b2[c] - m2[c] * i2;
  }
}

// ---------------------------------------------------------------------------
// x NCHW fp32 -> x_pad NHWC bf16 (padded + chunk-swizzled).
// grid 1792 (all-resident), 2 rows per block.
__global__ __launch_bounds__(256) void transform_kernel(const float* __restrict__ x,
                                                        u16* __restrict__ xpad) {
  __shared__ alignas(16) u16 t[7168];  // [112 px][64 ch], xor-swizzled bytes
  int tid = threadIdx.x;
#pragma unroll
  for (int jj = 0; jj < 2; ++jj) {
    int bid = blockIdx.x * 2 + jj;
    int b = bid / NH, h = bid % NH;
    const float* src = x + (long)b * 64 * 12544 + h * NW;
    f32x4 v[7];
#pragma unroll
    for (int it = 0; it < 7; ++it) {
      int fid = it * 256 + tid;  // 1792 = 64 ch * 28 quads
      int c = fid / 28, wq = fid % 28;
      v[it] = *reinterpret_cast<const f32x4*>(src + c * 12544 + wq * 4);
    }
#pragma unroll
    for (int it = 0; it < 7; ++it) {
      int fid = it * 256 + tid;
      int c = fid / 28, wq = fid % 28;
      int key = (wq & 7) << 4;
#pragma unroll
      for (int j = 0; j < 4; ++j) {
        int px = wq * 4 + j;
        *reinterpret_cast<u16*>((char*)t + px * 128 + ((c * 2) ^ key)) = f2b(v[it][j]);
      }
    }
    __syncthreads();
    int hp = h + 1;
    u16* rowb = xpad + (((long)b * PH + hp) * PW) * 64;
#pragma unroll
    for (int it = 0; it < 4; ++it) {
      int cidx = it * 256 + tid;
      if (cidx < 896) {  // 112 px * 8 chunks
        int c8 = cidx & 7, px = cidx >> 3;
        int lchunk = c8 ^ ((px >> 2) & 7);
        u16x8 vv =
            *reinterpret_cast<const u16x8*>((const char*)t + px * 128 + lchunk * 16);
        int wp = px + 1;
        int gkey = (2 * hp + wp) & 7;
        *reinterpret_cast<u16x8*>(rowb + (long)wp * 64 + ((c8 ^ gkey) * 8)) = vv;
      }
    }
    if (jj == 0) __syncthreads();  // t reused by second row
  }
}

// ---------------------------------------------------------------------------
// PASS 0 (persistent, 3 blocks/CU): grid 632 = 8*79, tiles sb + 632*j (n=4|5).
// x_pad -> bn1+relu -> y1_pad (swizzled NHWC bf16)
// ---------------------------------------------------------------------------
__global__ __launch_bounds__(256, 2) void conv_p0_kernel(
    const u16* __restrict__ xin, const u16* __restrict__ weff,
    const float* __restrict__ bnc, u16* __restrict__ ypad) {
  __shared__ alignas(64) char smem[2 * BUFB];

  int tid = threadIdx.x, lane = tid & 63, wv = tid >> 6;
  int ol = lane & 15, kg = (lane >> 4) & 3;
  const int o = wv * 16 + ol;

  float inv = bnc[o];
  float bias = bnc[64 + o];

  bf16x8 wf[3][3][2];  // 18 frags = 72 VGPR
#pragma unroll
  for (int kh = 0; kh < 3; ++kh)
#pragma unroll
    for (int kw = 0; kw < 3; ++kw)
#pragma unroll
      for (int ks = 0; ks < 2; ++ks)
        wf[kh][kw][ks] = __builtin_bit_cast(
            bf16x8, *reinterpret_cast<const u16x8*>(
                        weff + (((kh * 3 + kw) * 64 + o) * 64 + ks * 32 + kg * 8)));
  asm volatile("s_waitcnt vmcnt(0)" ::: "memory");
  SCHEDB;

  const int sb = (blockIdx.x & 7) * 79 + (blockIdx.x >> 3);  // 632 = 8*79
  const int n = (NTILES - sb + 631) / 632;                   // 4 or 5 tiles

  auto stage = [&](int tt, int boff) {
    int b = tt / 98;
    int r = tt % 98;
    int h0 = (r / 7) * 8, w0 = (r % 7) * 16;
    const char* src = (const char*)(xin + (((long)b * PH + h0) * PW + w0) * 64);
#pragma unroll
    for (int k = 0; k < 6; ++k) {
      int i = wv + k * 4;
      if (i < 23) {
        int cb = i * 64 + lane;
        if (cb < 1440) {
          int row = cb / 144, rem = cb % 144;
          gl_lds16(src + (long)row * PROWB + rem * 16, smem + boff + cb * 16);
        }
      }
    }
  };

  stage(sb, 0);
  asm volatile("" ::: "memory");
  if (n > 1) stage(sb + 632, BUFB);
  asm volatile("" ::: "memory");
  if (n > 1) {
    if (wv < 3) WAITVM(6);
    else        WAITVM(5);
  } else {
    WAITVM(0);
  }
  SCHEDB;

  for (int j = 0; j < n; ++j) {
    const int boff = (j & 1) * BUFB;
    const int tt = sb + j * 632;
    const int b = tt / 98;
    const int r = tt % 98;
    const int th0 = (r / 7) * 8, tw0 = (r % 7) * 16;

    __builtin_amdgcn_s_barrier();  // stage(j) landed & visible block-wide
    SCHEDB;

    f32x4 acc[8];
#pragma unroll
    for (int mf = 0; mf < 8; ++mf) acc[mf] = f32x4{0.f, 0.f, 0.f, 0.f};

#pragma unroll
    for (int kw = 0; kw < 3; ++kw)
#pragma unroll
      for (int ks = 0; ks < 2; ++ks) {
        const int col = ol + kw;
        const int sb8 = (ks << 2) | kg;
        bf16x8 a[4];
#pragma unroll
        for (int u = 0; u < 3; ++u) {
          int slot = sb8 ^ ((2 * u + col) & 7);
          a[u] = *reinterpret_cast<const bf16x8*>(smem + boff + (u * 18 + col) * 128 +
                                                  slot * 16);
        }
#pragma unroll
        for (int mf = 0; mf < 8; ++mf) {
          if (mf < 7) {
            int rr = mf + 3;
            int slot = sb8 ^ ((2 * rr + col) & 7);
            a[(mf + 3) & 3] = *reinterpret_cast<const bf16x8*>(
                smem + boff + (rr * 18 + col) * 128 + slot * 16);
          }
          acc[mf] = __builtin_amdgcn_mfma_f32_16x16x32_bf16(a[mf & 3], wf[0][kw][ks],
                                                            acc[mf], 0, 0, 0);
          acc[mf] = __builtin_amdgcn_mfma_f32_16x16x32_bf16(a[(mf + 1) & 3], wf[1][kw][ks],
                                                            acc[mf], 0, 0, 0);
          acc[mf] = __builtin_amdgcn_mfma_f32_16x16x32_bf16(a[(mf + 2) & 3], wf[2][kw][ks],
                                                            acc[mf], 0, 0, 0);
        }
      }

    SCHEDB;
    __builtin_amdgcn_s_barrier();  // all waves done reading buf: reuse as ys
    SCHEDB;
    u16* ys = reinterpret_cast<u16*>(smem + boff);  // [128 px][72]
#pragma unroll
    for (int mf = 0; mf < 8; ++mf)
#pragma unroll
      for (int rg = 0; rg < 4; ++rg) {
        int p = mf * 16 + kg * 4 + rg;
        ys[p * 72 + o] = f2b(fmaxf(acc[mf][rg] * inv + bias, 0.f));
      }
    asm volatile("s_waitcnt lgkmcnt(0)" ::: "memory");
    SCHEDB;
    __builtin_amdgcn_s_barrier();
    SCHEDB;
#pragma unroll
    for (int it = 0; it < 4; ++it) {
      int cidx = it * 256 + tid;  // 1024 chunks
      int c8 = cidx & 7, p = cidx >> 3;
      int hp = th0 + (p >> 4) + 1, wp = tw0 + (p & 15) + 1;
      int gkey = (2 * hp + wp) & 7;
      *reinterpret_cast<u16x8*>(ypad + (((long)b * PH + hp) * PW + wp) * 64 +
                                ((c8 ^ gkey) * 8)) =
          *reinterpret_cast<const u16x8*>(ys + p * 72 + c8 * 8);
    }

    if (j + 1 < n) {
      SCHEDB;
      __builtin_amdgcn_s_barrier();  // ys LDS reads done -> buf restageable
      SCHEDB;
      if (j + 2 < n) {
        stage(sb + (j + 2) * 632, boff);
        if (wv < 3) WAITVM(6);  // stage(j+1) done; stage(j+2) outstanding
        else        WAITVM(5);
      } else {
        WAITVM(0);  // stage(j+1) done (no further stages)
      }
      SCHEDB;
    }
  }
}

// ---------------------------------------------------------------------------
// PASS 1 (persistent, unchanged from R17): grid 512, tiles sb + 512*j.
// Per LDS buffer: [y1 window 23040 B][residual tile 16384 B] (RESID=1).
// Epilogue has ZERO VMEM loads -> stage(j+2) survives across compute.
// y1_pad -> bn2 + residual + relu -> out (NCHW f32)
// ---------------------------------------------------------------------------
template <int RESID>
__global__ __launch_bounds__(256, 2) void conv_p1_kernel(
    const u16* __restrict__ yin, const float* __restrict__ x,
    const u16* __restrict__ xres, const u16* __restrict__ weff,
    const float* __restrict__ bnc, float* __restrict__ out) {
  constexpr int BUF = RESID ? (BUFB + 16384) : BUFB;
  __shared__ alignas(64) char smem[2 * BUF];

  int tid = threadIdx.x, lane = tid & 63, wv = tid >> 6;
  int ol = lane & 15, kg = (lane >> 4) & 3;
  const int o = wv * 16 + ol;

  float inv = bnc[128 + o];
  float bias = bnc[192 + o];

  bf16x8 wf[3][3][2];
#pragma unroll
  for (int kh = 0; kh < 3; ++kh)
#pragma unroll
    for (int kw = 0; kw < 3; ++kw)
#pragma unroll
      for (int ks = 0; ks < 2; ++ks)
        wf[kh][kw][ks] = __builtin_bit_cast(
            bf16x8, *reinterpret_cast<const u16x8*>(
                        weff + (((kh * 3 + kw) * 64 + o) * 64 + ks * 32 + kg * 8)));
  asm volatile("s_waitcnt vmcnt(0)" ::: "memory");
  SCHEDB;

  const int sb = (blockIdx.x & 7) * 64 + (blockIdx.x >> 3);
  const int n = (NTILES - sb + 511) >> 9;

  auto stage = [&](int tt, int boff) {
    int b = tt / 98;
    int r = tt % 98;
    int h0 = (r / 7) * 8, w0 = (r % 7) * 16;
    const char* src = (const char*)(yin + (((long)b * PH + h0) * PW + w0) * 64);
#pragma unroll
    for (int k = 0; k < 6; ++k) {
      int i = wv + k * 4;
      if (i < 23) {
        int cb = i * 64 + lane;
        if (cb < 1440) {
          int row = cb / 144, rem = cb % 144;
          gl_lds16(src + (long)row * PROWB + rem * 16, smem + boff + cb * 16);
        }
      }
    }
    if constexpr (RESID) {
#pragma unroll
      for (int k = 0; k < 4; ++k) {
        int i = wv + k * 4;  // 0..15
        int cr = i * 64 + lane;
        int rp = cr >> 7, rem = cr & 127;
        gl_lds16((const char*)xres + (((long)b * PH + h0 + 1 + rp) * PW + w0 + 1) * 128 +
                     rem * 16,
                 smem + boff + BUFB + cr * 16);
      }
    }
  };
  auto gateS = [&] {
    if constexpr (RESID) {
      if (wv < 3) WAITVM(10); else WAITVM(9);
    } else {
      if (wv < 3) WAITVM(6); else WAITVM(5);
    }
  };

  stage(sb, 0);
  asm volatile("" ::: "memory");
  stage(sb + 512, BUF);
  asm volatile("" ::: "memory");
  gateS();
  SCHEDB;

  for (int j = 0; j < n; ++j) {
    const int boff = (j & 1) * BUF;
    const int tt = sb + (j << 9);
    const int b = tt / 98;
    const int r = tt % 98;
    const int th0 = (r / 7) * 8, tw0 = (r % 7) * 16;

    __builtin_amdgcn_s_barrier();  // stage(j) landed & visible block-wide
    SCHEDB;

    f32x4 acc[8];
#pragma unroll
    for (int mf = 0; mf < 8; ++mf) acc[mf] = f32x4{0.f, 0.f, 0.f, 0.f};

#pragma unroll
    for (int kw = 0; kw < 3; ++kw)
#pragma unroll
      for (int ks = 0; ks < 2; ++ks) {
        const int col = ol + kw;
        const int sb8 = (ks << 2) | kg;
        bf16x8 a[4];
#pragma unroll
        for (int u = 0; u < 3; ++u) {
          int slot = sb8 ^ ((2 * u + col) & 7);
          a[u] = *reinterpret_cast<const bf16x8*>(smem + boff + (u * 18 + col) * 128 +
                                                  slot * 16);
        }
#pragma unroll
        for (int mf = 0; mf < 8; ++mf) {
          if (mf < 7) {
            int rr = mf + 3;
            int slot = sb8 ^ ((2 * rr + col) & 7);
            a[(mf + 3) & 3] = *reinterpret_cast<const bf16x8*>(
                smem + boff + (rr * 18 + col) * 128 + slot * 16);
          }
          acc[mf] = __builtin_amdgcn_mfma_f32_16x16x32_bf16(a[mf & 3], wf[0][kw][ks],
                                                            acc[mf], 0, 0, 0);
          acc[mf] = __builtin_amdgcn_mfma_f32_16x16x32_bf16(a[(mf + 1) & 3], wf[1][kw][ks],
                                                            acc[mf], 0, 0, 0);
          acc[mf] = __builtin_amdgcn_mfma_f32_16x16x32_bf16(a[(mf + 2) & 3], wf[2][kw][ks],
                                                            acc[mf], 0, 0, 0);
        }
      }

    // ---- epilogue: bn2 + residual + relu -> direct NCHW f32x4 stores ----
    if constexpr (RESID) {
#pragma unroll
      for (int mf = 0; mf < 8; ++mf) {
        int h = th0 + mf, hp = h + 1;
        f32x4 vv;
#pragma unroll
        for (int rg = 0; rg < 4; ++rg) {
          int wq = kg * 4 + rg, wp = tw0 + wq + 1;
          int key = (2 * hp + wp) & 7;
          u16 bv = *reinterpret_cast<const u16*>(
              smem + boff + BUFB + (mf * 16 + wq) * 128 + (((o >> 3) ^ key) * 16) +
              (o & 7) * 2);
          vv[rg] = fmaxf(acc[mf][rg] * inv + bias + b2f(bv), 0.f);
        }
        *reinterpret_cast<f32x4*>(out + (((b * 64 + o) * NH + h) * NW + tw0 + kg * 4)) =
            vv;
      }
    } else {
#pragma unroll
      for (int half = 0; half < 2; ++half) {
        f32x4 xr[4];
#pragma unroll
        for (int m = 0; m < 4; ++m) {
          int h = th0 + half * 4 + m;
          xr[m] = *reinterpret_cast<const f32x4*>(
              x + (((b * 64 + o) * NH + h) * NW + tw0 + kg * 4));
        }
#pragma unroll
        for (int m = 0; m < 4; ++m) {
          int mf = half * 4 + m;
          int h = th0 + mf;
          f32x4 vv;
#pragma unroll
          for (int rg = 0; rg < 4; ++rg)
            vv[rg] = fmaxf(acc[mf][rg] * inv + bias + xr[m][rg], 0.f);
          *reinterpret_cast<f32x4*>(out + (((b * 64 + o) * NH + h) * NW + tw0 + kg * 4)) =
              vv;
        }
      }
    }

    if (j + 1 < n) {
      SCHEDB;
      __builtin_amdgcn_s_barrier();  // buf reads (A + res) done -> restageable
      SCHEDB;
      if (j + 2 < n) {
        stage(sb + ((j + 2) << 9), boff);
        gateS();  // stage(j+1) done; stage(j+2) stays outstanding
      } else {
        WAITVM(0);  // stage(j+1) done (no further stages)
      }
      SCHEDB;
    }
  }
}

// ---------------------------------------------------------------------------
extern "C" void kernel_launch(void* const* d_in, const int* in_sizes, int n_in,
                              void* d_out, int out_size, void* d_ws, size_t ws_size,
                              hipStream_t stream) {
  const float* x = (const float*)d_in[0];
  const float* w1 = (const float*)d_in[1];
  const float* w2 = (const float*)d_in[2];
  const float* alpha = (const float*)d_in[3];
  const float* g1 = (const float*)d_in[4];
  const float* b1 = (const float*)d_in[5];
  const float* m1 = (const float*)d_in[6];
  const float* v1 = (const float*)d_in[7];
  const float* g2 = (const float*)d_in[8];
  const float* b2 = (const float*)d_in[9];
  const float* m2 = (const float*)d_in[10];
  const float* v2 = (const float*)d_in[11];
  float* out = (float*)d_out;

  char* ws = (char*)d_ws;
  u16* weff1 = (u16*)ws;                 // 73728 B
  u16* weff2 = (u16*)(ws + 73728);       // 73728 B
  float* bnc = (float*)(ws + 147456);    // 1024 B
  u16* y1pad = (u16*)(ws + 148480);      // 53231616 B
  const size_t PADB = 53231616ull;       // 32*114*114*64*2
  bool big = ws_size >= 148480ull + 2ull * PADB;
  // big ws: xpad in ws (stays live through P1 -> bf16 residual source).
  // small ws: xpad in d_out (dead before P1 writes) -> fp32-x residual.
  u16* xpad = big ? (u16*)(ws + 148480 + PADB) : (u16*)d_out;

  setup_kernel<<<1048, 256, 0, stream>>>(xpad, y1pad, w1, w2, alpha, g1, b1, m1,
                                         v1, g2, b2, m2, v2, weff1, weff2, bnc);
  transform_kernel<<<1792, 256, 0, stream>>>(x, xpad);
  conv_p0_kernel<<<632, 256, 0, stream>>>(xpad, weff1, bnc, y1pad);
  if (big)
    conv_p1_kernel<1><<<512, 256, 0, stream>>>(y1pad, x, xpad, weff2, bnc, out);
  else
    conv_p1_kernel<0><<<512, 256, 0, stream>>>(y1pad, x, nullptr, weff2, bnc, out);
}

// Round 19
// 119.682 us; speedup vs baseline: 1.0179x; 1.0179x over previous
//
#include <hip/hip_runtime.h>

// BasicBlock: y = relu(bn2(conv2(relu(bn1(conv1(x, we1))), we2)) + x)
// we{1,2} = sum_e alpha[e]*w{1,2}[e].
//
// bf16 implicit-GEMM conv, mfma_f32_16x16x32_bf16, staged from padded,
// chunk-swizzled NHWC bf16 images (slot = c8 ^ ((2h+w)&7) within 128B px).
//
// R19 = R17 verbatim (session's measured optimum, 119.3us). R18's three
// "mechanical fixes" (P0 grid 632 w/ 3 blk/CU, transform 2-rows/block,
// merged setup) netted -2.5us -> reverted. Structure summary:
//  - persistent conv blocks: grid 512 (2/CU exact), tiles sb + 512*j,
//    rolling 2-buffer LDS, stage(j+2) issued in epilogue(j) -> every
//    compute covered, zero scheduling tail.
//  - 8Mx1N wave decomposition: wf 18 bf16x8 = 72 VGPR resident, rolling
//    4-slot A window -> VGPR 128, spill-free.
//  - P1 residual staged to LDS as bf16 from xpad (epilogue VMEM-free).
// Counted gates (loads-only sound): P0 vmcnt(6|5), P1 vmcnt(10|9).

typedef __bf16 bf16x8 __attribute__((ext_vector_type(8)));
typedef float f32x4 __attribute__((ext_vector_type(4)));
typedef unsigned short u16;
typedef u16 u16x8 __attribute__((ext_vector_type(8)));

#define NH 112
#define NW 112
#define PH 114
#define PW 114
#define PROWB (PW * 128)  // 14592 bytes per padded NHWC row
#define BUFB 23040        // y1/x window buffer: 10 rows * 18 px * 128 B
#define NTILES 3136       // 32 images * 98 tiles

#define WAITVM(n) asm volatile("s_waitcnt vmcnt(" #n ")" ::: "memory")
#define SCHEDB __builtin_amdgcn_sched_barrier(0)

__device__ __forceinline__ u16 f2b(float f) {
  unsigned u = __builtin_bit_cast(unsigned, f);
  u += 0x7FFFu + ((u >> 16) & 1u);
  return (u16)(u >> 16);
}
__device__ __forceinline__ float b2f(u16 b) {
  unsigned u = ((unsigned)b) << 16;
  return __builtin_bit_cast(float, u);
}

__device__ __forceinline__ void gl_lds16(const void* g, void* l) {
  __builtin_amdgcn_global_load_lds(
      (const __attribute__((address_space(1))) unsigned int*)g,
      (__attribute__((address_space(3))) unsigned int*)l, 16, 0, 0);
}

// ---------------------------------------------------------------------------
__global__ void border_zero(u16* __restrict__ a, u16* __restrict__ bbuf) {
  int idx = blockIdx.x * 256 + threadIdx.x;  // 2*32*452*8 = 231424 chunks
  if (idx >= 231424) return;
  int c8 = idx & 7;
  int t = idx >> 3;
  int buf = t >= 14464;
  t -= buf * 14464;
  int img = t / 452, e = t % 452;
  int h, w;
  if (e < 114) { h = 0; w = e; }
  else if (e < 228) { h = 113; w = e - 114; }
  else if (e < 340) { h = e - 227; w = 0; }
  else { h = e - 339; w = 113; }
  u16* base = buf ? bbuf : a;
  u16x8 z = {0, 0, 0, 0, 0, 0, 0, 0};
  *reinterpret_cast<u16x8*>(base + (((long)img * PH + h) * PW + w) * 64 + c8 * 8) = z;
}

// ---------------------------------------------------------------------------
// x NCHW fp32 -> x_pad NHWC bf16 (padded + chunk-swizzled). block = (b,h).
__global__ __launch_bounds__(256) void transform_kernel(const float* __restrict__ x,
                                                        u16* __restrict__ xpad) {
  __shared__ alignas(16) u16 t[7168];  // [112 px][64 ch], xor-swizzled bytes
  int tid = threadIdx.x, bid = blockIdx.x;
  int b = bid / NH, h = bid % NH;
  const float* src = x + (long)b * 64 * 12544 + h * NW;
  f32x4 v[7];
#pragma unroll
  for (int it = 0; it < 7; ++it) {
    int fid = it * 256 + tid;  // 1792 = 64 ch * 28 quads
    int c = fid / 28, wq = fid % 28;
    v[it] = *reinterpret_cast<const f32x4*>(src + c * 12544 + wq * 4);
  }
#pragma unroll
  for (int it = 0; it < 7; ++it) {
    int fid = it * 256 + tid;
    int c = fid / 28, wq = fid % 28;
    int key = (wq & 7) << 4;
#pragma unroll
    for (int j = 0; j < 4; ++j) {
      int px = wq * 4 + j;
      *reinterpret_cast<u16*>((char*)t + px * 128 + ((c * 2) ^ key)) = f2b(v[it][j]);
    }
  }
  __syncthreads();
  int hp = h + 1;
  u16* rowb = xpad + (((long)b * PH + hp) * PW) * 64;
#pragma unroll
  for (int it = 0; it < 4; ++it) {
    int cidx = it * 256 + tid;
    if (cidx < 896) {  // 112 px * 8 chunks
      int c8 = cidx & 7, px = cidx >> 3;
      int lchunk = c8 ^ ((px >> 2) & 7);
      u16x8 vv = *reinterpret_cast<const u16x8*>((const char*)t + px * 128 + lchunk * 16);
      int wp = px + 1;
      int gkey = (2 * hp + wp) & 7;
      *reinterpret_cast<u16x8*>(rowb + (long)wp * 64 + ((c8 ^ gkey) * 8)) = vv;
    }
  }
}

// ---------------------------------------------------------------------------
// fold experts -> w_eff bf16 [kpos][o][i] + folded BN constants
__global__ void prep_kernel(
    const float* __restrict__ w1, const float* __restrict__ w2,
    const float* __restrict__ alpha,
    const float* __restrict__ g1, const float* __restrict__ b1,
    const float* __restrict__ m1, const float* __restrict__ v1,
    const float* __restrict__ g2, const float* __restrict__ b2,
    const float* __restrict__ m2, const float* __restrict__ v2,
    u16* __restrict__ weff1, u16* __restrict__ weff2, float* __restrict__ bnc) {
  int idx = blockIdx.x * 256 + threadIdx.x;  // 36864
  if (idx < 36864) {
    int i = idx & 63;
    int o = (idx >> 6) & 63;
    int kpos = idx >> 12;
    int base = (o * 64 + i) * 9 + kpos;  // src [E][O][I][3][3]
    float a1 = 0.f, a2 = 0.f;
#pragma unroll
    for (int e = 0; e < 10; ++e) {
      float al = alpha[e];
      a1 += al * w1[e * 36864 + base];
      a2 += al * w2[e * 36864 + base];
    }
    weff1[idx] = f2b(a1);
    weff2[idx] = f2b(a2);
  }
  if (blockIdx.x == 0 && threadIdx.x < 64) {
    int c = threadIdx.x;
    float i1 = g1[c] * rsqrtf(v1[c] + 1e-5f);
    float i2 = g2[c] * rsqrtf(v2[c] + 1e-5f);
    bnc[c] = i1;
    bnc[64 + c] = b1[c] - m1[c] * i1;
    bnc[128 + c] = i2;
    bnc[192 + c] = b2[c] - m2[c] * i2;
  }
}

// ---------------------------------------------------------------------------
// PASS 0 (persistent): grid 512, block walks tiles sb + 512*j (n = 6|7).
// x_pad -> bn1+relu -> y1_pad (swizzled NHWC bf16)
// ---------------------------------------------------------------------------
__global__ __launch_bounds__(256, 2) void conv_p0_kernel(
    const u16* __restrict__ xin, const u16* __restrict__ weff,
    const float* __restrict__ bnc, u16* __restrict__ ypad) {
  __shared__ alignas(64) char smem[2 * BUFB];

  int tid = threadIdx.x, lane = tid & 63, wv = tid >> 6;
  int ol = lane & 15, kg = (lane >> 4) & 3;
  const int o = wv * 16 + ol;

  float inv = bnc[o];
  float bias = bnc[64 + o];

  bf16x8 wf[3][3][2];  // 18 frags = 72 VGPR
#pragma unroll
  for (int kh = 0; kh < 3; ++kh)
#pragma unroll
    for (int kw = 0; kw < 3; ++kw)
#pragma unroll
      for (int ks = 0; ks < 2; ++ks)
        wf[kh][kw][ks] = __builtin_bit_cast(
            bf16x8, *reinterpret_cast<const u16x8*>(
                        weff + (((kh * 3 + kw) * 64 + o) * 64 + ks * 32 + kg * 8)));
  asm volatile("s_waitcnt vmcnt(0)" ::: "memory");
  SCHEDB;

  const int sb = (blockIdx.x & 7) * 64 + (blockIdx.x >> 3);  // 512 = 8*64
  const int n = (NTILES - sb + 511) >> 9;                    // 6 or 7 tiles

  auto stage = [&](int tt, int boff) {
    int b = tt / 98;
    int r = tt % 98;
    int h0 = (r / 7) * 8, w0 = (r % 7) * 16;
    const char* src = (const char*)(xin + (((long)b * PH + h0) * PW + w0) * 64);
#pragma unroll
    for (int k = 0; k < 6; ++k) {
      int i = wv + k * 4;
      if (i < 23) {
        int cb = i * 64 + lane;
        if (cb < 1440) {
          int row = cb / 144, rem = cb % 144;
          gl_lds16(src + (long)row * PROWB + rem * 16, smem + boff + cb * 16);
        }
      }
    }
  };

  stage(sb, 0);
  asm volatile("" ::: "memory");
  stage(sb + 512, BUFB);
  asm volatile("" ::: "memory");
  if (wv < 3) WAITVM(6);
  else        WAITVM(5);
  SCHEDB;

  for (int j = 0; j < n; ++j) {
    const int boff = (j & 1) * BUFB;
    const int tt = sb + (j << 9);
    const int b = tt / 98;
    const int r = tt % 98;
    const int th0 = (r / 7) * 8, tw0 = (r % 7) * 16;

    __builtin_amdgcn_s_barrier();  // stage(j) landed & visible block-wide
    SCHEDB;

    f32x4 acc[8];
#pragma unroll
    for (int mf = 0; mf < 8; ++mf) acc[mf] = f32x4{0.f, 0.f, 0.f, 0.f};

#pragma unroll
    for (int kw = 0; kw < 3; ++kw)
#pragma unroll
      for (int ks = 0; ks < 2; ++ks) {
        const int col = ol + kw;
        const int sb8 = (ks << 2) | kg;
        bf16x8 a[4];
#pragma unroll
        for (int u = 0; u < 3; ++u) {
          int slot = sb8 ^ ((2 * u + col) & 7);
          a[u] = *reinterpret_cast<const bf16x8*>(smem + boff + (u * 18 + col) * 128 +
                                                  slot * 16);
        }
#pragma unroll
        for (int mf = 0; mf < 8; ++mf) {
          if (mf < 7) {
            int rr = mf + 3;
            int slot = sb8 ^ ((2 * rr + col) & 7);
            a[(mf + 3) & 3] = *reinterpret_cast<const bf16x8*>(
                smem + boff + (rr * 18 + col) * 128 + slot * 16);
          }
          acc[mf] = __builtin_amdgcn_mfma_f32_16x16x32_bf16(a[mf & 3], wf[0][kw][ks],
                                                            acc[mf], 0, 0, 0);
          acc[mf] = __builtin_amdgcn_mfma_f32_16x16x32_bf16(a[(mf + 1) & 3], wf[1][kw][ks],
                                                            acc[mf], 0, 0, 0);
          acc[mf] = __builtin_amdgcn_mfma_f32_16x16x32_bf16(a[(mf + 2) & 3], wf[2][kw][ks],
                                                            acc[mf], 0, 0, 0);
        }
      }

    SCHEDB;
    __builtin_amdgcn_s_barrier();  // all waves done reading buf: reuse as ys
    SCHEDB;
    u16* ys = reinterpret_cast<u16*>(smem + boff);  // [128 px][72]
#pragma unroll
    for (int mf = 0; mf < 8; ++mf)
#pragma unroll
      for (int rg = 0; rg < 4; ++rg) {
        int p = mf * 16 + kg * 4 + rg;
        ys[p * 72 + o] = f2b(fmaxf(acc[mf][rg] * inv + bias, 0.f));
      }
    asm volatile("s_waitcnt lgkmcnt(0)" ::: "memory");
    SCHEDB;
    __builtin_amdgcn_s_barrier();
    SCHEDB;
#pragma unroll
    for (int it = 0; it < 4; ++it) {
      int cidx = it * 256 + tid;  // 1024 chunks
      int c8 = cidx & 7, p = cidx >> 3;
      int hp = th0 + (p >> 4) + 1, wp = tw0 + (p & 15) + 1;
      int gkey = (2 * hp + wp) & 7;
      *reinterpret_cast<u16x8*>(ypad + (((long)b * PH + hp) * PW + wp) * 64 +
                                ((c8 ^ gkey) * 8)) =
          *reinterpret_cast<const u16x8*>(ys + p * 72 + c8 * 8);
    }

    if (j + 1 < n) {
      SCHEDB;
      __builtin_amdgcn_s_barrier();  // ys LDS reads done -> buf restageable
      SCHEDB;
      if (j + 2 < n) {
        stage(sb + ((j + 2) << 9), boff);
        if (wv < 3) WAITVM(6);  // stage(j+1) done; stage(j+2) outstanding
        else        WAITVM(5);
      } else {
        WAITVM(0);  // stage(j+1) done (no further stages)
      }
      SCHEDB;
    }
  }
}

// ---------------------------------------------------------------------------
// PASS 1 (persistent): grid 512, tiles sb + 512*j. Per LDS buffer:
// [y1 window 23040 B][residual tile 16384 B] (RESID=1). Epilogue has ZERO
// VMEM loads (residual via ds_read) -> stage(j+2) survives across compute.
// y1_pad -> bn2 + residual + relu -> out (NCHW f32)
// ---------------------------------------------------------------------------
template <int RESID>
__global__ __launch_bounds__(256, 2) void conv_p1_kernel(
    const u16* __restrict__ yin, const float* __restrict__ x,
    const u16* __restrict__ xres, const u16* __restrict__ weff,
    const float* __restrict__ bnc, float* __restrict__ out) {
  constexpr int BUF = RESID ? (BUFB + 16384) : BUFB;
  __shared__ alignas(64) char smem[2 * BUF];

  int tid = threadIdx.x, lane = tid & 63, wv = tid >> 6;
  int ol = lane & 15, kg = (lane >> 4) & 3;
  const int o = wv * 16 + ol;

  float inv = bnc[128 + o];
  float bias = bnc[192 + o];

  bf16x8 wf[3][3][2];
#pragma unroll
  for (int kh = 0; kh < 3; ++kh)
#pragma unroll
    for (int kw = 0; kw < 3; ++kw)
#pragma unroll
      for (int ks = 0; ks < 2; ++ks)
        wf[kh][kw][ks] = __builtin_bit_cast(
            bf16x8, *reinterpret_cast<const u16x8*>(
                        weff + (((kh * 3 + kw) * 64 + o) * 64 + ks * 32 + kg * 8)));
  asm volatile("s_waitcnt vmcnt(0)" ::: "memory");
  SCHEDB;

  const int sb = (blockIdx.x & 7) * 64 + (blockIdx.x >> 3);
  const int n = (NTILES - sb + 511) >> 9;

  auto stage = [&](int tt, int boff) {
    int b = tt / 98;
    int r = tt % 98;
    int h0 = (r / 7) * 8, w0 = (r % 7) * 16;
    const char* src = (const char*)(yin + (((long)b * PH + h0) * PW + w0) * 64);
#pragma unroll
    for (int k = 0; k < 6; ++k) {
      int i = wv + k * 4;
      if (i < 23) {
        int cb = i * 64 + lane;
        if (cb < 1440) {
          int row = cb / 144, rem = cb % 144;
          gl_lds16(src + (long)row * PROWB + rem * 16, smem + boff + cb * 16);
        }
      }
    }
    if constexpr (RESID) {
#pragma unroll
      for (int k = 0; k < 4; ++k) {
        int i = wv + k * 4;  // 0..15
        int cr = i * 64 + lane;
        int rp = cr >> 7, rem = cr & 127;
        gl_lds16((const char*)xres + (((long)b * PH + h0 + 1 + rp) * PW + w0 + 1) * 128 +
                     rem * 16,
                 smem + boff + BUFB + cr * 16);
      }
    }
  };
  auto gateS = [&] {
    if constexpr (RESID) {
      if (wv < 3) WAITVM(10); else WAITVM(9);
    } else {
      if (wv < 3) WAITVM(6); else WAITVM(5);
    }
  };

  stage(sb, 0);
  asm volatile("" ::: "memory");
  stage(sb + 512, BUF);
  asm volatile("" ::: "memory");
  gateS();
  SCHEDB;

  for (int j = 0; j < n; ++j) {
    const int boff = (j & 1) * BUF;
    const int tt = sb + (j << 9);
    const int b = tt / 98;
    const int r = tt % 98;
    const int th0 = (r / 7) * 8, tw0 = (r % 7) * 16;

    __builtin_amdgcn_s_barrier();  // stage(j) landed & visible block-wide
    SCHEDB;

    f32x4 acc[8];
#pragma unroll
    for (int mf = 0; mf < 8; ++mf) acc[mf] = f32x4{0.f, 0.f, 0.f, 0.f};

#pragma unroll
    for (int kw = 0; kw < 3; ++kw)
#pragma unroll
      for (int ks = 0; ks < 2; ++ks) {
        const int col = ol + kw;
        const int sb8 = (ks << 2) | kg;
        bf16x8 a[4];
#pragma unroll
        for (int u = 0; u < 3; ++u) {
          int slot = sb8 ^ ((2 * u + col) & 7);
          a[u] = *reinterpret_cast<const bf16x8*>(smem + boff + (u * 18 + col) * 128 +
                                                  slot * 16);
        }
#pragma unroll
        for (int mf = 0; mf < 8; ++mf) {
          if (mf < 7) {
            int rr = mf + 3;
            int slot = sb8 ^ ((2 * rr + col) & 7);
            a[(mf + 3) & 3] = *reinterpret_cast<const bf16x8*>(
                smem + boff + (rr * 18 + col) * 128 + slot * 16);
          }
          acc[mf] = __builtin_amdgcn_mfma_f32_16x16x32_bf16(a[mf & 3], wf[0][kw][ks],
                                                            acc[mf], 0, 0, 0);
          acc[mf] = __builtin_amdgcn_mfma_f32_16x16x32_bf16(a[(mf + 1) & 3], wf[1][kw][ks],
                                                            acc[mf], 0, 0, 0);
          acc[mf] = __builtin_amdgcn_mfma_f32_16x16x32_bf16(a[(mf + 2) & 3], wf[2][kw][ks],
                                                            acc[mf], 0, 0, 0);
        }
      }

    // ---- epilogue: bn2 + residual + relu -> direct NCHW f32x4 stores ----
    if constexpr (RESID) {
#pragma unroll
      for (int mf = 0; mf < 8; ++mf) {
        int h = th0 + mf, hp = h + 1;
        f32x4 vv;
#pragma unroll
        for (int rg = 0; rg < 4; ++rg) {
          int wq = kg * 4 + rg, wp = tw0 + wq + 1;
          int key = (2 * hp + wp) & 7;
          u16 bv = *reinterpret_cast<const u16*>(
              smem + boff + BUFB + (mf * 16 + wq) * 128 + (((o >> 3) ^ key) * 16) +
              (o & 7) * 2);
          vv[rg] = fmaxf(acc[mf][rg] * inv + bias + b2f(bv), 0.f);
        }
        *reinterpret_cast<f32x4*>(out + (((b * 64 + o) * NH + h) * NW + tw0 + kg * 4)) =
            vv;
      }
    } else {
#pragma unroll
      for (int half = 0; half < 2; ++half) {
        f32x4 xr[4];
#pragma unroll
        for (int m = 0; m < 4; ++m) {
          int h = th0 + half * 4 + m;
          xr[m] = *reinterpret_cast<const f32x4*>(
              x + (((b * 64 + o) * NH + h) * NW + tw0 + kg * 4));
        }
#pragma unroll
        for (int m = 0; m < 4; ++m) {
          int mf = half * 4 + m;
          int h = th0 + mf;
          f32x4 vv;
#pragma unroll
          for (int rg = 0; rg < 4; ++rg)
            vv[rg] = fmaxf(acc[mf][rg] * inv + bias + xr[m][rg], 0.f);
          *reinterpret_cast<f32x4*>(out + (((b * 64 + o) * NH + h) * NW + tw0 + kg * 4)) =
              vv;
        }
      }
    }

    if (j + 1 < n) {
      SCHEDB;
      __builtin_amdgcn_s_barrier();  // buf reads (A + res) done -> restageable
      SCHEDB;
      if (j + 2 < n) {
        stage(sb + ((j + 2) << 9), boff);
        gateS();  // stage(j+1) done; stage(j+2) stays outstanding
      } else {
        WAITVM(0);  // stage(j+1) done (no further stages)
      }
      SCHEDB;
    }
  }
}

// ---------------------------------------------------------------------------
extern "C" void kernel_launch(void* const* d_in, const int* in_sizes, int n_in,
                              void* d_out, int out_size, void* d_ws, size_t ws_size,
                              hipStream_t stream) {
  const float* x = (const float*)d_in[0];
  const float* w1 = (const float*)d_in[1];
  const float* w2 = (const float*)d_in[2];
  const float* alpha = (const float*)d_in[3];
  const float* g1 = (const float*)d_in[4];
  const float* b1 = (const float*)d_in[5];
  const float* m1 = (const float*)d_in[6];
  const float* v1 = (const float*)d_in[7];
  const float* g2 = (const float*)d_in[8];
  const float* b2 = (const float*)d_in[9];
  const float* m2 = (const float*)d_in[10];
  const float* v2 = (const float*)d_in[11];
  float* out = (float*)d_out;

  char* ws = (char*)d_ws;
  u16* weff1 = (u16*)ws;                 // 73728 B
  u16* weff2 = (u16*)(ws + 73728);       // 73728 B
  float* bnc = (float*)(ws + 147456);    // 1024 B
  u16* y1pad = (u16*)(ws + 148480);      // 53231616 B
  const size_t PADB = 53231616ull;       // 32*114*114*64*2
  bool big = ws_size >= 148480ull + 2ull * PADB;
  // big ws: xpad in ws (stays live through P1 -> bf16 residual source).
  // small ws: xpad in d_out (dead before P1 writes) -> fp32-x residual.
  u16* xpad = big ? (u16*)(ws + 148480 + PADB) : (u16*)d_out;

  border_zero<<<904, 256, 0, stream>>>(xpad, y1pad);
  transform_kernel<<<32 * NH, 256, 0, stream>>>(x, xpad);
  prep_kernel<<<144, 256, 0, stream>>>(w1, w2, alpha, g1, b1, m1, v1,
                                       g2, b2, m2, v2, weff1, weff2, bnc);
  conv_p0_kernel<<<512, 256, 0, stream>>>(xpad, weff1, bnc, y1pad);
  if (big)
    conv_p1_kernel<1><<<512, 256, 0, stream>>>(y1pad, x, xpad, weff2, bnc, out);
  else
    conv_p1_kernel<0><<<512, 256, 0, stream>>>(y1pad, x, nullptr, weff2, bnc, out);
}